// Round 3
// baseline (5251.763 us; speedup 1.0000x reference)
//
#include <hip/hip_runtime.h>
#include <stdint.h>

// Problem constants
#define SEQ   2048
#define DE    256
#define DXX   64
#define DIN   320      // DE + DX
#define HH    256      // hidden per direction
#define G4    1024     // 4*HH
#define NT    64       // tags

// Workspace layout (float32 slot indices)
// GX [2][SEQ][G4] ; H [2][SEQ][HH] ; SLOT u64[2][2][256] (double-buffered
// tagged h exchange: [dir][buf][elem]) ; FE [SEQ][NT] ; BP u8 [SEQ][NT]
static constexpr size_t OFF_GX = 0;
static constexpr size_t OFF_H  = OFF_GX + (size_t)2 * SEQ * G4;        // 4194304
static constexpr size_t HSTR   = (size_t)SEQ * HH;                     // 524288
static constexpr size_t OFF_SL = OFF_H + 2 * HSTR;                     // 5242880 (8B-aligned)
static constexpr size_t OFF_FE = OFF_SL + 2048;                        // 5244928
static constexpr size_t OFF_BP = OFF_FE + (size_t)SEQ * NT;            // 5376000
static constexpr size_t WS_NEEDED_BYTES = OFF_BP * 4 + (size_t)SEQ * NT; // ~21.6 MB

// ---------------------------------------------------------------------------
// K0: reset both slot buffers to (h=0, tag=0). Buffer 0 == h_{-1} for t=0.
// ---------------------------------------------------------------------------
__global__ __launch_bounds__(256) void k_init(unsigned long long* __restrict__ slot) {
  const int tid = threadIdx.x;
  #pragma unroll
  for (int b = 0; b < 4; ++b) slot[b * 256 + tid] = 0ull;   // 2 dirs x 2 bufs
}

// ---------------------------------------------------------------------------
// K1: fused gather + gx = x @ w_ih.T + (b_ih + b_hh), both directions.
// grid (SEQ/32, G4/256, 2), block 512.
// ---------------------------------------------------------------------------
__global__ __launch_bounds__(512) void k_gx(
    const int* __restrict__ sent, const int* __restrict__ extra,
    const float* __restrict__ emb, const float* __restrict__ xemb,
    const float* __restrict__ wf, const float* __restrict__ wb,
    const float* __restrict__ bif, const float* __restrict__ bhf,
    const float* __restrict__ bib, const float* __restrict__ bhb,
    float* __restrict__ GX) {
  __shared__ __align__(16) float xs[32][36];    // [kk][s_local]
  __shared__ __align__(16) float wl[32][260];   // [kk][r_local]
  const int tid = threadIdx.x;
  const int s0 = blockIdx.x * 32, r0 = blockIdx.y * 256, dir = blockIdx.z;
  const float* W = dir ? wb : wf;
  const int tids = tid & 7;        // s-group (4 s each)
  const int tidr = tid >> 3;       // r-group (4 r each), 0..63
  float acc[4][4];
  #pragma unroll
  for (int a = 0; a < 4; ++a)
    #pragma unroll
    for (int b = 0; b < 4; ++b) acc[a][b] = 0.f;

  for (int kc = 0; kc < 10; ++kc) {
    const int k0 = kc * 32;
    __syncthreads();
    for (int e = tid; e < 1024; e += 512) {     // x tile (fused gather)
      int kk = e & 31, sl = e >> 5;
      int s = s0 + sl;
      int src = dir ? (SEQ - 1 - s) : s;
      int k = k0 + kk;
      float v;
      if (k < DE) v = emb[(size_t)sent[src] * DE + k];
      else        v = xemb[(size_t)extra[src] * DXX + (k - DE)];
      xs[kk][sl] = v;
    }
    for (int e = tid; e < 8192; e += 512) {     // w tile
      int kk = e & 31, rl = e >> 5;
      wl[kk][rl] = W[(size_t)(r0 + rl) * DIN + k0 + kk];
    }
    __syncthreads();
    #pragma unroll
    for (int kk = 0; kk < 32; ++kk) {
      float4 xv = *(const float4*)&xs[kk][4 * tids];
      float4 wv = *(const float4*)&wl[kk][4 * tidr];
      acc[0][0] += xv.x * wv.x; acc[0][1] += xv.x * wv.y; acc[0][2] += xv.x * wv.z; acc[0][3] += xv.x * wv.w;
      acc[1][0] += xv.y * wv.x; acc[1][1] += xv.y * wv.y; acc[1][2] += xv.y * wv.z; acc[1][3] += xv.y * wv.w;
      acc[2][0] += xv.z * wv.x; acc[2][1] += xv.z * wv.y; acc[2][2] += xv.z * wv.z; acc[2][3] += xv.z * wv.w;
      acc[3][0] += xv.w * wv.x; acc[3][1] += xv.w * wv.y; acc[3][2] += xv.w * wv.z; acc[3][3] += xv.w * wv.w;
    }
  }
  const float* BI = dir ? bib : bif;
  const float* BH = dir ? bhb : bhf;
  float4 b1 = *(const float4*)&BI[r0 + 4 * tidr];
  float4 b2 = *(const float4*)&BH[r0 + 4 * tidr];
  float bx = b1.x + b2.x, by = b1.y + b2.y, bz = b1.z + b2.z, bw = b1.w + b2.w;
  #pragma unroll
  for (int ss = 0; ss < 4; ++ss) {
    int s = s0 + 4 * tids + ss;
    float4 o;
    o.x = acc[ss][0] + bx; o.y = acc[ss][1] + by; o.z = acc[ss][2] + bz; o.w = acc[ss][3] + bw;
    *(float4*)&GX[((size_t)dir * SEQ + s) * G4 + r0 + 4 * tidr] = o;
  }
}

// ---------------------------------------------------------------------------
// K2: persistent BiLSTM, 16-way partition + DOUBLE-BUFFERED tagged-slot
// exchange. grid 32 (= 2 dirs x 16 parts), block 256.
//
// Round-3 changes (theory: VGPR_Count=52 proves the one-shot weight pin
// failed -> w_hh restreams 64KB/block/step from L2 ~1000cy/step; tail still
// pays bar2 + 5 serial transcendentals):
//  (1) IN-LOOP weight pin: the empty asm "+v" executes EVERY iteration, so
//      each iteration's w value flows through the asm -> the allocator can
//      no longer rematerialize the loads; weights must stay in 64 VGPRs.
//      Discriminator: VGPR_Count must jump to >=110.
//  (2) Element-major row remap: rowQ = g*256 + p*16 + e with g=(tid>>2)&3,
//      e=tid>>4. An element's 4 gate-rows occupy 16 CONTIGUOUS lanes
//      (lanes 16e+4g, q in the low 2 bits), so after the 2-shfl_xor
//      quarter-reduce (bit-exact (p0+p1)+(p2+p3) tree), the gate
//      nonlinearities run lane-parallel (2 exec-masked paths instead of 5
//      serial libm calls) and the i/f/g/o gather is 3 __shfl - the entire
//      tail is wave-local: bar2 + psum/gacc LDS stages deleted. One barrier
//      per step; hl double-buffered by t&1 (drift-safe by barrier
//      collectivity: a wave cannot reach the write of buffer B at step t+1
//      before bar1(t), which every wave reaches only after its reads of
//      buffer B at step t-1 retired).
//  (3) Own-slot shortcut: owners write their h directly into hl[(t+1)&1];
//      the 16 own slots are never polled (removes an own-publish L3 round
//      trip from bar1's dependency set). Remote-safety of the tagged-slot
//      protocol is unchanged (publisher still reads all REMOTE tag-t slots
//      before overwriting tag t-1; remote readers' consumption is implied
//      by their publishers' tag-t publishes, which we did observe).
//  All FP expressions / association trees / expf/tanhf calls are identical
//  per element to round 2 -> h trajectory bit-exact -> tags unchanged.
//
// Exchange protocol (unchanged core): reader of step t polls buf[t&1] slot
// until tag==t (data rides in the same 8B atom). Publisher writes (h_t, t+1)
// into buf[(t+1)&1]. Max skew = 1 step => equality-poll can never miss.
// ---------------------------------------------------------------------------
__global__ __launch_bounds__(256, 1) void k_lstm16(
    const float* __restrict__ whf, const float* __restrict__ whb,
    const float* __restrict__ GX, float* __restrict__ H,
    unsigned long long* __restrict__ slot) {
  const int dir = blockIdx.x >> 4;
  const int p   = blockIdx.x & 15;
  const int tid = threadIdx.x;
  const int q   = tid & 3;             // k-quarter (64 h each)
  const int g   = (tid >> 2) & 3;      // gate i,f,g,o of this thread's row
  const int e   = tid >> 4;            // element 0..15 (also publisher id of polled slot)
  const int rowQ = (g << 8) | (p << 4) | e;   // matvec row (gate-major storage)
  const int lane = tid & 63;
  const int Lb   = lane & 48;          // base lane of this element's 16-lane group

  const float4* w4g =
      (const float4*)((dir ? whb : whf) + (size_t)rowQ * HH) + q * 16;
  float4 w[16];
  #pragma unroll
  for (int i = 0; i < 16; ++i) w[i] = w4g[i];

  const float* gxp = GX + (size_t)dir * SEQ * G4 + rowQ;
  float* Hd = H + (size_t)dir * HSTR;
  unsigned long long* sl = slot + dir * 512;   // [buf=2][256]

  // double-buffered, bank-staggered h broadcast: element j at [j>>6][j&63];
  // quarter rows start 272B apart -> the 4 broadcast b128 addresses per
  // matvec read hit disjoint bank quads (measured 0 conflicts, R1/R2).
  __shared__ __align__(16) float hl[2][4][68];
  float c = 0.f;                       // valid at owner lanes ((tid&15)==0)
  int budget = 1 << 18;                // pure failsafe (race impossible)
  const bool ownpoll = (e == p);       // slots [16p,16p+16) are published by us

  if (ownpoll) hl[0][tid >> 6][tid & 63] = 0.f;   // h_{-1}=0 own entries
  // (ordered before first matvec read by bar1 of t=0)

  for (int t = 0; t < SEQ; ++t) {
    float gxv = 0.f;
    if (q == 0) gxv = gxp[(size_t)t * G4];   // pre-poll prefetch (HBM/L2/L3)
    if (!ownpoll) {  // poll slot tid in buffer t&1 for h_{t-1}[tid]
      unsigned long long* sp = &sl[(t & 1) * 256 + tid];
      unsigned long long v;
      do {
        v = __hip_atomic_load(sp, __ATOMIC_RELAXED, __HIP_MEMORY_SCOPE_AGENT);
      } while ((unsigned)(v >> 32) != (unsigned)t && --budget > 0);
      union { unsigned u; float f; } cv; cv.u = (unsigned)v;
      hl[t & 1][tid >> 6][tid & 63] = cv.f;
    }
    // Re-pin weights EVERY iteration: value flows through the asm each step,
    // so rematerializing the loads cannot bypass it -> forced residency.
    #pragma unroll
    for (int i = 0; i < 16; ++i)
      asm volatile("" : "+v"(w[i].x), "+v"(w[i].y), "+v"(w[i].z), "+v"(w[i].w));
    __syncthreads();                   // the ONLY barrier per step
    const float4* h4 = (const float4*)hl[t & 1][q];
    float a0 = 0.f, a1 = 0.f, a2 = 0.f, a3 = 0.f;
    #pragma unroll
    for (int i = 0; i < 16; ++i) {
      float4 wv = w[i];
      float4 hv = h4[i];
      a0 += wv.x * hv.x; a1 += wv.y * hv.y; a2 += wv.z * hv.z; a3 += wv.w * hv.w;
    }
    float sr = (a0 + a1) + (a2 + a3);          // quarter partial p_q
    sr += __shfl_xor(sr, 1);                   // p0+p1 | p2+p3
    sr += __shfl_xor(sr, 2);                   // (p0+p1)+(p2+p3) - exact old tree
    float s = gxv + sr;                        // full row sum at q==0 lanes
    float sig = 1.f / (1.f + expf(-s));        // same expr as before
    float th  = tanhf(s);
    float gated = (g == 2) ? th : sig;         // per-row nonlinearity
    float fg = __shfl(gated, Lb + 4);          // f-row gated (its q==0 lane)
    float gg = __shfl(gated, Lb + 8);          // g-row gated
    float og = __shfl(gated, Lb + 12);         // o-row gated
    if ((tid & 15) == 0) {   // owner lane of element e: state update+publish
      c = fg * c + gated * gg;                 // gated == sigmoid(i-row)
      float h = og * tanhf(c);
      int jj = (p << 4) | e;
      union { float f; unsigned u; } hu; hu.f = h;
      unsigned long long pk =
          ((unsigned long long)(unsigned)(t + 1) << 32) | hu.u;
      __hip_atomic_store(&sl[((t + 1) & 1) * 256 + jj], pk, __ATOMIC_RELAXED,
                         __HIP_MEMORY_SCOPE_AGENT);   // publish FIRST
      hl[(t + 1) & 1][jj >> 6][jj & 63] = h;   // own-entry LDS shortcut
      Hd[(size_t)t * HH + jj] = h;             // plain store for k_feats
    }
  }
}

// ---------------------------------------------------------------------------
// K3: feats = [hf, hb_rev] @ fc_w.T + fc_b.  grid SEQ/16, block 256.
// ---------------------------------------------------------------------------
__global__ __launch_bounds__(256) void k_feats(
    const float* __restrict__ HF, const float* __restrict__ HB,
    const float* __restrict__ fcw, const float* __restrict__ fcb,
    float* __restrict__ FE) {
  __shared__ float hlds[16][512];
  __shared__ float wl[64][65];
  const int tid = threadIdx.x;
  const int s0 = blockIdx.x * 16;
  for (int e = tid; e < 16 * 512; e += 256) {
    int sl = e >> 9, k = e & 511;
    float v = (k < HH) ? HF[(size_t)(s0 + sl) * HH + k]
                       : HB[(size_t)(SEQ - 1 - (s0 + sl)) * HH + (k - HH)];
    hlds[sl][k] = v;
  }
  const int j = tid & 63, sg = tid >> 6;
  float acc[4];
  #pragma unroll
  for (int q = 0; q < 4; ++q) acc[q] = fcb[j];
  for (int kc = 0; kc < 8; ++kc) {
    __syncthreads();
    for (int e = tid; e < 4096; e += 256) {
      int kk = e & 63, jj = e >> 6;
      wl[kk][jj] = fcw[(size_t)jj * 512 + kc * 64 + kk];
    }
    __syncthreads();
    #pragma unroll 8
    for (int kk = 0; kk < 64; ++kk) {
      float wv = wl[kk][j];
      int kg = kc * 64 + kk;
      #pragma unroll
      for (int q = 0; q < 4; ++q) acc[q] += hlds[4 * sg + q][kg] * wv;
    }
  }
  #pragma unroll
  for (int q = 0; q < 4; ++q)
    FE[(size_t)(s0 + 4 * sg + q) * NT + j] = acc[q];
}

// ---------------------------------------------------------------------------
// K4: Viterbi. 1 block x 256 threads (4 waves split the 64-way max).
// numpy-faithful: v = (score[i]+trans[i][j]) + feats[t][j], strict-> first-max.
// ---------------------------------------------------------------------------
__global__ __launch_bounds__(256) void k_viterbi(
    const float* __restrict__ feats, const float* __restrict__ start,
    const float* __restrict__ endv, const float* __restrict__ trans,
    unsigned char* __restrict__ bp, int* __restrict__ out) {
  __shared__ float tr[64 * 64];
  __shared__ float sc[64];
  __shared__ float pval[4][64];
  __shared__ int pidx[4][64];
  const int tid = threadIdx.x;
  for (int e = tid; e < 4096; e += 256) tr[e] = trans[e];
  if (tid < 64) sc[tid] = start[tid] + feats[tid];
  __syncthreads();
  const int w = tid >> 6, j = tid & 63;
  for (int t = 1; t < SEQ; ++t) {
    float fj = feats[t * NT + j];
    float best = -3.0e38f; int bi = 0;
    const int ibase = w << 4;
    #pragma unroll
    for (int ii = 0; ii < 16; ++ii) {
      int i = ibase + ii;
      float v = (sc[i] + tr[(i << 6) | j]) + fj;
      if (v > best) { best = v; bi = i; }
    }
    pval[w][j] = best; pidx[w][j] = bi;
    __syncthreads();
    if (w == 0) {
      float b = pval[0][j]; int x = pidx[0][j];
      if (pval[1][j] > b) { b = pval[1][j]; x = pidx[1][j]; }
      if (pval[2][j] > b) { b = pval[2][j]; x = pidx[2][j]; }
      if (pval[3][j] > b) { b = pval[3][j]; x = pidx[3][j]; }
      bp[t * NT + j] = (unsigned char)x;
      sc[j] = b;
    }
    __syncthreads();
  }
  if (tid == 0) {
    float best = -3.0e38f; int bt = 0;
    for (int i = 0; i < 64; ++i) {
      float v = sc[i] + endv[i];
      if (v > best) { best = v; bt = i; }
    }
    out[SEQ - 1] = bt;
    int tag = bt;
    for (int t = SEQ - 1; t >= 1; --t) {
      tag = bp[t * NT + tag];
      out[t - 1] = tag;
    }
  }
}

// ---------------------------------------------------------------------------
extern "C" void kernel_launch(void* const* d_in, const int* in_sizes, int n_in,
                              void* d_out, int out_size, void* d_ws, size_t ws_size,
                              hipStream_t stream) {
  // --- Defensive guards: any mismatch -> fail visibly (absmax), never fault.
  if (n_in < 19) return;
  if (in_sizes[0] != SEQ || in_sizes[1] != SEQ) return;              // sentence, extra
  if (in_sizes[2] != 1 || in_sizes[3] != 1) return;                  // b, e scalars
  if (in_sizes[4] != 100000 * DE) return;                            // emb
  if (in_sizes[5] != 1000 * DXX) return;                             // extra_emb
  if (in_sizes[6] != G4 * DIN || in_sizes[7] != G4 * HH) return;     // w_ih_f, w_hh_f
  if (in_sizes[8] != G4 || in_sizes[9] != G4) return;                // b_ih_f, b_hh_f
  if (in_sizes[10] != G4 * DIN || in_sizes[11] != G4 * HH) return;   // w_ih_b, w_hh_b
  if (in_sizes[14] != NT * 512 || in_sizes[15] != NT) return;        // fc_w, fc_b
  if (in_sizes[16] != NT || in_sizes[17] != NT) return;              // crf_start, crf_end
  if (in_sizes[18] != NT * NT) return;                               // crf_trans
  if (out_size < SEQ) return;
  if (ws_size < WS_NEEDED_BYTES) return;

  const int*   sent = (const int*)d_in[0];
  const int*   extra = (const int*)d_in[1];
  const float* emb  = (const float*)d_in[4];
  const float* xemb = (const float*)d_in[5];
  const float* wihf = (const float*)d_in[6];
  const float* whhf = (const float*)d_in[7];
  const float* bihf = (const float*)d_in[8];
  const float* bhhf = (const float*)d_in[9];
  const float* wihb = (const float*)d_in[10];
  const float* whhb = (const float*)d_in[11];
  const float* bihb = (const float*)d_in[12];
  const float* bhhb = (const float*)d_in[13];
  const float* fcw  = (const float*)d_in[14];
  const float* fcb  = (const float*)d_in[15];
  const float* cst  = (const float*)d_in[16];
  const float* cen  = (const float*)d_in[17];
  const float* ctr  = (const float*)d_in[18];

  float* ws = (float*)d_ws;
  float* GX = ws + OFF_GX;
  float* H  = ws + OFF_H;
  unsigned long long* SLOT = (unsigned long long*)(ws + OFF_SL);
  float* FE = ws + OFF_FE;
  unsigned char* BP = (unsigned char*)(ws + OFF_BP);

  k_init<<<1, 256, 0, stream>>>(SLOT);
  k_gx<<<dim3(SEQ / 32, G4 / 256, 2), 512, 0, stream>>>(
      sent, extra, emb, xemb, wihf, wihb, bihf, bhhf, bihb, bhhb, GX);
  k_lstm16<<<32, 256, 0, stream>>>(whhf, whhb, GX, H, SLOT);
  k_feats<<<SEQ / 16, 256, 0, stream>>>(H, H + HSTR, fcw, fcb, FE);
  k_viterbi<<<1, 256, 0, stream>>>(FE, cst, cen, ctr, BP, (int*)d_out);
}

// Round 4
// 4983.503 us; speedup vs baseline: 1.0538x; 1.0538x over previous
//
#include <hip/hip_runtime.h>
#include <stdint.h>

// Problem constants
#define SEQ   2048
#define DE    256
#define DXX   64
#define DIN   320      // DE + DX
#define HH    256      // hidden per direction
#define G4    1024     // 4*HH
#define NT    64       // tags

// Workspace layout (float32 slot indices)
// GX [2][SEQ][G4] ; H [2][SEQ][HH] ; SLOT u64[2][2][256] (double-buffered
// tagged h exchange: [dir][buf][elem]) ; FE [SEQ][NT] ; BP u8 [SEQ][NT]
static constexpr size_t OFF_GX = 0;
static constexpr size_t OFF_H  = OFF_GX + (size_t)2 * SEQ * G4;        // 4194304
static constexpr size_t HSTR   = (size_t)SEQ * HH;                     // 524288
static constexpr size_t OFF_SL = OFF_H + 2 * HSTR;                     // 5242880 (8B-aligned)
static constexpr size_t OFF_FE = OFF_SL + 2048;                        // 5244928
static constexpr size_t OFF_BP = OFF_FE + (size_t)SEQ * NT;            // 5376000
static constexpr size_t WS_NEEDED_BYTES = OFF_BP * 4 + (size_t)SEQ * NT; // ~21.6 MB

// ---------------------------------------------------------------------------
// K0: reset both slot buffers to (h=0, tag=0). Buffer 0 == h_{-1} for t=0.
// ---------------------------------------------------------------------------
__global__ __launch_bounds__(256) void k_init(unsigned long long* __restrict__ slot) {
  const int tid = threadIdx.x;
  #pragma unroll
  for (int b = 0; b < 4; ++b) slot[b * 256 + tid] = 0ull;   // 2 dirs x 2 bufs
}

// ---------------------------------------------------------------------------
// K1: fused gather + gx = x @ w_ih.T + (b_ih + b_hh), both directions.
// grid (SEQ/32, G4/256, 2), block 512.
// ---------------------------------------------------------------------------
__global__ __launch_bounds__(512) void k_gx(
    const int* __restrict__ sent, const int* __restrict__ extra,
    const float* __restrict__ emb, const float* __restrict__ xemb,
    const float* __restrict__ wf, const float* __restrict__ wb,
    const float* __restrict__ bif, const float* __restrict__ bhf,
    const float* __restrict__ bib, const float* __restrict__ bhb,
    float* __restrict__ GX) {
  __shared__ __align__(16) float xs[32][36];    // [kk][s_local]
  __shared__ __align__(16) float wl[32][260];   // [kk][r_local]
  const int tid = threadIdx.x;
  const int s0 = blockIdx.x * 32, r0 = blockIdx.y * 256, dir = blockIdx.z;
  const float* W = dir ? wb : wf;
  const int tids = tid & 7;        // s-group (4 s each)
  const int tidr = tid >> 3;       // r-group (4 r each), 0..63
  float acc[4][4];
  #pragma unroll
  for (int a = 0; a < 4; ++a)
    #pragma unroll
    for (int b = 0; b < 4; ++b) acc[a][b] = 0.f;

  for (int kc = 0; kc < 10; ++kc) {
    const int k0 = kc * 32;
    __syncthreads();
    for (int e = tid; e < 1024; e += 512) {     // x tile (fused gather)
      int kk = e & 31, sl = e >> 5;
      int s = s0 + sl;
      int src = dir ? (SEQ - 1 - s) : s;
      int k = k0 + kk;
      float v;
      if (k < DE) v = emb[(size_t)sent[src] * DE + k];
      else        v = xemb[(size_t)extra[src] * DXX + (k - DE)];
      xs[kk][sl] = v;
    }
    for (int e = tid; e < 8192; e += 512) {     // w tile
      int kk = e & 31, rl = e >> 5;
      wl[kk][rl] = W[(size_t)(r0 + rl) * DIN + k0 + kk];
    }
    __syncthreads();
    #pragma unroll
    for (int kk = 0; kk < 32; ++kk) {
      float4 xv = *(const float4*)&xs[kk][4 * tids];
      float4 wv = *(const float4*)&wl[kk][4 * tidr];
      acc[0][0] += xv.x * wv.x; acc[0][1] += xv.x * wv.y; acc[0][2] += xv.x * wv.z; acc[0][3] += xv.x * wv.w;
      acc[1][0] += xv.y * wv.x; acc[1][1] += xv.y * wv.y; acc[1][2] += xv.y * wv.z; acc[1][3] += xv.y * wv.w;
      acc[2][0] += xv.z * wv.x; acc[2][1] += xv.z * wv.y; acc[2][2] += xv.z * wv.z; acc[2][3] += xv.z * wv.w;
      acc[3][0] += xv.w * wv.x; acc[3][1] += xv.w * wv.y; acc[3][2] += xv.w * wv.z; acc[3][3] += xv.w * wv.w;
    }
  }
  const float* BI = dir ? bib : bif;
  const float* BH = dir ? bhb : bhf;
  float4 b1 = *(const float4*)&BI[r0 + 4 * tidr];
  float4 b2 = *(const float4*)&BH[r0 + 4 * tidr];
  float bx = b1.x + b2.x, by = b1.y + b2.y, bz = b1.z + b2.z, bw = b1.w + b2.w;
  #pragma unroll
  for (int ss = 0; ss < 4; ++ss) {
    int s = s0 + 4 * tids + ss;
    float4 o;
    o.x = acc[ss][0] + bx; o.y = acc[ss][1] + by; o.z = acc[ss][2] + bz; o.w = acc[ss][3] + bw;
    *(float4*)&GX[((size_t)dir * SEQ + s) * G4 + r0 + 4 * tidr] = o;
  }
}

// ---------------------------------------------------------------------------
// K2: persistent BiLSTM, 16-way partition + DOUBLE-BUFFERED tagged-slot
// exchange. grid 32 (= 2 dirs x 16 parts), block 256.
//
// R2 structure (best measured: 3327us, bank-conflicts 0, 2 barriers/step)
// + three latency-targeted deltas. Step budget at R2: ~3900cy of which
// ~3300cy is exchange wait (VALUBusy 1.8% => ~560cy issued); so:
//  (1) PIPELINED 4-DEEP POLL: the R2 poll retry period = full agent-load
//      latency L (load->cmp->branch->load). Keep 4 independent atomic loads
//      in flight, check round-robin: checks spaced ~L/4, discovery drops
//      from ~2L worst-case to ~L+L/4. Predicted -500..700cy/step. Extra
//      poll traffic is 8B/lane per ~L/4 on a 2KB hot set - benign.
//  (2) Gate-parallel tail INSIDE wave 0: after the combine, lane g*16+e
//      applies its row's nonlinearity (identical formulas: sigmoid for
//      i/f/o rows, tanh for g row), owner lane e gathers f/g/o via 3
//      intra-wave __shfl. Deletes the gacc LDS round-trip and runs 2
//      transcendental paths instead of 5 serial. Bit-exact: same exprs,
//      same association, same values as the old gacc[g*16+e] path.
//  (3) Own-slot shortcut: threads polling elements owned by this block
//      ((tid>>4)==p) skip the poll; owner lanes write their h directly
//      into hl at the tail. Ordering: owner writes hl[own] after bar2(t)
//      (all step-t reads retired) and before bar1(t+1) (all step-t+1 reads
//      after it). Disjoint from non-owner poll writes. Removes 16
//      self-round-trips per block from bar1's dependency set.
// Weight residency: one-shot pin as R2; evidence (VGPR=52) says weights
// live in AGPRs (unified file, ~1-2cy access) - good enough, stop chasing.
//
// Exchange protocol (unchanged): reader of step t polls buf[t&1] slot tid
// until tag==t (data rides in the same 8B atom). Publisher writes (h_t, t+1)
// into buf[(t+1)&1] - only overwrites tag t-1, and a publisher cannot reach
// tag t+1 before every block consumed tag t. Max skew = 1 step =>
// equality-poll can never miss.
// ---------------------------------------------------------------------------
__global__ __launch_bounds__(256, 1) void k_lstm16(
    const float* __restrict__ whf, const float* __restrict__ whb,
    const float* __restrict__ GX, float* __restrict__ H,
    unsigned long long* __restrict__ slot) {
  const int dir = blockIdx.x >> 4;
  const int p   = blockIdx.x & 15;
  const int tid = threadIdx.x;
  const int rr  = tid >> 2;            // local row 0..63
  const int q   = tid & 3;             // k-quarter
  const int gq  = rr >> 4;             // gate of local row
  const int joq = rr & 15;             // local elem of local row
  const int rowQ = (gq << 8) | (p << 4) | joq;      // matvec row
  const int rowC = ((tid >> 4) << 8) | (p << 4) | (tid & 15);  // combine row

  const float4* w4g =
      (const float4*)((dir ? whb : whf) + (size_t)rowQ * HH) + q * 16;
  float4 w[16];
  #pragma unroll
  for (int i = 0; i < 16; ++i) w[i] = w4g[i];
  // One-shot pin (R2): keeps the loads hoisted; allocator parks them in
  // AGPRs (VGPR_Count 52) which is ~free to access. Leave it be.
  #pragma unroll
  for (int i = 0; i < 16; ++i)
    asm volatile("" : "+v"(w[i].x), "+v"(w[i].y), "+v"(w[i].z), "+v"(w[i].w));

  const float* gxc = GX + (size_t)dir * SEQ * G4 + rowC;  // combine threads
  float* Hd = H + (size_t)dir * HSTR;
  unsigned long long* sl = slot + dir * 512;   // [buf=2][256]

  // bank-staggered h broadcast: element e at [e>>6][e&63]; quarter q's 64
  // floats start at 272 B offsets -> the 4 b128 addresses per matvec read
  // hit disjoint bank quads (conflict-free, measured 0 since R1).
  __shared__ __align__(16) float hl[4][68];
  __shared__ float psum[256];
  float c = 0.f;                       // valid in tid<16
  int budget = 1 << 18;                // pure failsafe (race impossible)
  const bool ownpoll = ((tid >> 4) == p);   // this thread's polled element is ours

  if (ownpoll) hl[tid >> 6][tid & 63] = 0.f;   // h_{-1}=0 for own elements
  // (ordered before the first matvec read by bar1 of t=0)

  for (int t = 0; t < SEQ; ++t) {
    float gxv = 0.f;
    if (tid < 64) gxv = gxc[(size_t)t * G4];   // pre-poll prefetch (HBM/L2)
    if (!ownpoll) {  // pipelined 4-deep poll of slot tid, buffer t&1
      unsigned long long* sp = &sl[(t & 1) * 256 + tid];
      const unsigned tw = (unsigned)t;
      unsigned long long v;
      unsigned long long v0 = __hip_atomic_load(sp, __ATOMIC_RELAXED, __HIP_MEMORY_SCOPE_AGENT);
      unsigned long long v1 = __hip_atomic_load(sp, __ATOMIC_RELAXED, __HIP_MEMORY_SCOPE_AGENT);
      unsigned long long v2 = __hip_atomic_load(sp, __ATOMIC_RELAXED, __HIP_MEMORY_SCOPE_AGENT);
      unsigned long long v3 = __hip_atomic_load(sp, __ATOMIC_RELAXED, __HIP_MEMORY_SCOPE_AGENT);
      for (;;) {
        if ((unsigned)(v0 >> 32) == tw) { v = v0; break; }
        v0 = __hip_atomic_load(sp, __ATOMIC_RELAXED, __HIP_MEMORY_SCOPE_AGENT);
        if ((unsigned)(v1 >> 32) == tw) { v = v1; break; }
        v1 = __hip_atomic_load(sp, __ATOMIC_RELAXED, __HIP_MEMORY_SCOPE_AGENT);
        if ((unsigned)(v2 >> 32) == tw) { v = v2; break; }
        v2 = __hip_atomic_load(sp, __ATOMIC_RELAXED, __HIP_MEMORY_SCOPE_AGENT);
        if ((unsigned)(v3 >> 32) == tw) { v = v3; break; }
        v3 = __hip_atomic_load(sp, __ATOMIC_RELAXED, __HIP_MEMORY_SCOPE_AGENT);
        if (--budget <= 0) { v = v3; break; }
      }
      union { unsigned u; float f; } cv; cv.u = (unsigned)v;
      hl[tid >> 6][tid & 63] = cv.f;
    }
    __syncthreads();                   // bar1: hl ready
    const float4* h4 = (const float4*)(hl[q]);
    float a0 = 0.f, a1 = 0.f, a2 = 0.f, a3 = 0.f;
    #pragma unroll
    for (int i = 0; i < 16; ++i) {
      float4 wv = w[i];
      float4 hv = h4[i];
      a0 += wv.x * hv.x; a1 += wv.y * hv.y; a2 += wv.z * hv.z; a3 += wv.w * hv.w;
    }
    psum[tid] = (a0 + a1) + (a2 + a3);
    __syncthreads();                   // bar2: psum ready
    if (tid < 64) {   // wave 0: combine + gate-parallel nonlinearity + tail
      float s = gxv + ((psum[4 * tid] + psum[4 * tid + 1]) +
                       (psum[4 * tid + 2] + psum[4 * tid + 3]));
      const int gg_ = tid >> 4;        // gate of row rowC (0=i,1=f,2=g,3=o)
      const int ee  = tid & 15;        // element
      float sig = 1.f / (1.f + expf(-s));   // identical expr to old path
      float th  = tanhf(s);
      float gated = (gg_ == 2) ? th : sig;  // per-row nonlinearity
      float fg = __shfl(gated, 16 + ee);    // f-row value for element ee
      float gv = __shfl(gated, 32 + ee);    // g-row value
      float og = __shfl(gated, 48 + ee);    // o-row value
      if (tid < 16) {  // owner lane of element ee: state update + publish
        c = fg * c + gated * gv;            // gated == sigmoid(i-row)
        float h = og * tanhf(c);
        int jj = (p << 4) | tid;
        union { float f; unsigned u; } hu; hu.f = h;
        unsigned long long pk =
            ((unsigned long long)(unsigned)(t + 1) << 32) | hu.u;
        __hip_atomic_store(&sl[((t + 1) & 1) * 256 + jj], pk, __ATOMIC_RELAXED,
                           __HIP_MEMORY_SCOPE_AGENT);   // publish FIRST
        hl[jj >> 6][jj & 63] = h;            // own-entry LDS shortcut
        Hd[(size_t)t * HH + jj] = h;         // plain store for k_feats
      }
    }
  }
}

// ---------------------------------------------------------------------------
// K3: feats = [hf, hb_rev] @ fc_w.T + fc_b.  grid SEQ/16, block 256.
// ---------------------------------------------------------------------------
__global__ __launch_bounds__(256) void k_feats(
    const float* __restrict__ HF, const float* __restrict__ HB,
    const float* __restrict__ fcw, const float* __restrict__ fcb,
    float* __restrict__ FE) {
  __shared__ float hlds[16][512];
  __shared__ float wl[64][65];
  const int tid = threadIdx.x;
  const int s0 = blockIdx.x * 16;
  for (int e = tid; e < 16 * 512; e += 256) {
    int sl = e >> 9, k = e & 511;
    float v = (k < HH) ? HF[(size_t)(s0 + sl) * HH + k]
                       : HB[(size_t)(SEQ - 1 - (s0 + sl)) * HH + (k - HH)];
    hlds[sl][k] = v;
  }
  const int j = tid & 63, sg = tid >> 6;
  float acc[4];
  #pragma unroll
  for (int q = 0; q < 4; ++q) acc[q] = fcb[j];
  for (int kc = 0; kc < 8; ++kc) {
    __syncthreads();
    for (int e = tid; e < 4096; e += 256) {
      int kk = e & 63, jj = e >> 6;
      wl[kk][jj] = fcw[(size_t)jj * 512 + kc * 64 + kk];
    }
    __syncthreads();
    #pragma unroll 8
    for (int kk = 0; kk < 64; ++kk) {
      float wv = wl[kk][j];
      int kg = kc * 64 + kk;
      #pragma unroll
      for (int q = 0; q < 4; ++q) acc[q] += hlds[4 * sg + q][kg] * wv;
    }
  }
  #pragma unroll
  for (int q = 0; q < 4; ++q)
    FE[(size_t)(s0 + 4 * sg + q) * NT + j] = acc[q];
}

// ---------------------------------------------------------------------------
// K4: Viterbi. 1 block x 256 threads (4 waves split the 64-way max).
// numpy-faithful: v = (score[i]+trans[i][j]) + feats[t][j], strict-> first-max.
// ---------------------------------------------------------------------------
__global__ __launch_bounds__(256) void k_viterbi(
    const float* __restrict__ feats, const float* __restrict__ start,
    const float* __restrict__ endv, const float* __restrict__ trans,
    unsigned char* __restrict__ bp, int* __restrict__ out) {
  __shared__ float tr[64 * 64];
  __shared__ float sc[64];
  __shared__ float pval[4][64];
  __shared__ int pidx[4][64];
  const int tid = threadIdx.x;
  for (int e = tid; e < 4096; e += 256) tr[e] = trans[e];
  if (tid < 64) sc[tid] = start[tid] + feats[tid];
  __syncthreads();
  const int w = tid >> 6, j = tid & 63;
  for (int t = 1; t < SEQ; ++t) {
    float fj = feats[t * NT + j];
    float best = -3.0e38f; int bi = 0;
    const int ibase = w << 4;
    #pragma unroll
    for (int ii = 0; ii < 16; ++ii) {
      int i = ibase + ii;
      float v = (sc[i] + tr[(i << 6) | j]) + fj;
      if (v > best) { best = v; bi = i; }
    }
    pval[w][j] = best; pidx[w][j] = bi;
    __syncthreads();
    if (w == 0) {
      float b = pval[0][j]; int x = pidx[0][j];
      if (pval[1][j] > b) { b = pval[1][j]; x = pidx[1][j]; }
      if (pval[2][j] > b) { b = pval[2][j]; x = pidx[2][j]; }
      if (pval[3][j] > b) { b = pval[3][j]; x = pidx[3][j]; }
      bp[t * NT + j] = (unsigned char)x;
      sc[j] = b;
    }
    __syncthreads();
  }
  if (tid == 0) {
    float best = -3.0e38f; int bt = 0;
    for (int i = 0; i < 64; ++i) {
      float v = sc[i] + endv[i];
      if (v > best) { best = v; bt = i; }
    }
    out[SEQ - 1] = bt;
    int tag = bt;
    for (int t = SEQ - 1; t >= 1; --t) {
      tag = bp[t * NT + tag];
      out[t - 1] = tag;
    }
  }
}

// ---------------------------------------------------------------------------
extern "C" void kernel_launch(void* const* d_in, const int* in_sizes, int n_in,
                              void* d_out, int out_size, void* d_ws, size_t ws_size,
                              hipStream_t stream) {
  // --- Defensive guards: any mismatch -> fail visibly (absmax), never fault.
  if (n_in < 19) return;
  if (in_sizes[0] != SEQ || in_sizes[1] != SEQ) return;              // sentence, extra
  if (in_sizes[2] != 1 || in_sizes[3] != 1) return;                  // b, e scalars
  if (in_sizes[4] != 100000 * DE) return;                            // emb
  if (in_sizes[5] != 1000 * DXX) return;                             // extra_emb
  if (in_sizes[6] != G4 * DIN || in_sizes[7] != G4 * HH) return;     // w_ih_f, w_hh_f
  if (in_sizes[8] != G4 || in_sizes[9] != G4) return;                // b_ih_f, b_hh_f
  if (in_sizes[10] != G4 * DIN || in_sizes[11] != G4 * HH) return;   // w_ih_b, w_hh_b
  if (in_sizes[14] != NT * 512 || in_sizes[15] != NT) return;        // fc_w, fc_b
  if (in_sizes[16] != NT || in_sizes[17] != NT) return;              // crf_start, crf_end
  if (in_sizes[18] != NT * NT) return;                               // crf_trans
  if (out_size < SEQ) return;
  if (ws_size < WS_NEEDED_BYTES) return;

  const int*   sent = (const int*)d_in[0];
  const int*   extra = (const int*)d_in[1];
  const float* emb  = (const float*)d_in[4];
  const float* xemb = (const float*)d_in[5];
  const float* wihf = (const float*)d_in[6];
  const float* whhf = (const float*)d_in[7];
  const float* bihf = (const float*)d_in[8];
  const float* bhhf = (const float*)d_in[9];
  const float* wihb = (const float*)d_in[10];
  const float* whhb = (const float*)d_in[11];
  const float* bihb = (const float*)d_in[12];
  const float* bhhb = (const float*)d_in[13];
  const float* fcw  = (const float*)d_in[14];
  const float* fcb  = (const float*)d_in[15];
  const float* cst  = (const float*)d_in[16];
  const float* cen  = (const float*)d_in[17];
  const float* ctr  = (const float*)d_in[18];

  float* ws = (float*)d_ws;
  float* GX = ws + OFF_GX;
  float* H  = ws + OFF_H;
  unsigned long long* SLOT = (unsigned long long*)(ws + OFF_SL);
  float* FE = ws + OFF_FE;
  unsigned char* BP = (unsigned char*)(ws + OFF_BP);

  k_init<<<1, 256, 0, stream>>>(SLOT);
  k_gx<<<dim3(SEQ / 32, G4 / 256, 2), 512, 0, stream>>>(
      sent, extra, emb, xemb, wihf, wihb, bihf, bhhf, bihb, bhhb, GX);
  k_lstm16<<<32, 256, 0, stream>>>(whhf, whhb, GX, H, SLOT);
  k_feats<<<SEQ / 16, 256, 0, stream>>>(H, H + HSTR, fcw, fcb, FE);
  k_viterbi<<<1, 256, 0, stream>>>(FE, cst, cen, ctr, BP, (int*)d_out);
}